// Round 3
// baseline (2271.430 us; speedup 1.0000x reference)
//
#include <hip/hip_runtime.h>

#define DIM   256
#define RANK  64
#define NSEG0 192                 // dim - rank = smallest segment length
#define N0    14304               // sum_{j=0}^{63} (192+j)  (complex pairs per batch)
#define TILE  32                  // rows staged per LDS tile

// Fused single-pass formulation (see round-2 derivation).
// OUTPUT CONVENTION (established by rounds 1-2): d_out holds
// batch*dim*rank = 16,777,216 float32 = the REAL PART of the complex
// (1024,256,64) Stiefel matrix, C-order. (Round-1 memory fault proves the
// allocation is 64 MiB; harness's np reference astype(float32) drops imag.)
//
// Lane c owns final column c (created at step j0 = 63-c). Stream rows
// i = 0..255 once; carry all 63 scan states A[j] in registers; rowJ values
// generated on the fly from running products S (cumprod sin t) and
// E (prod exp(i p)). Per row, scans applied in increasing j:
//   i == 192+j : scan j deposits its carry (columns c >= 64-j)
//   i <  192+j : scan j rotates (v, A[j])   (columns c >= 64-j)
//   i >  192+j : scan j finished, dead.
// Trig (cos t, sin t, cos p, sin p) staged per 32-row tile for all 64
// segments into 32 KiB LDS; hot-loop reads are wave-broadcast.
__global__ __launch_bounds__(64, 1)
void stiefel_fused(const float* __restrict__ theta, float* __restrict__ out,
                   long long out_limit)
{
    const int b = blockIdx.x;
    const int c = threadIdx.x;                       // final column, 0..63

    const float2* tb = (const float2*)theta + (size_t)b * N0;   // (t,p) pairs
    const long long obase = (long long)b * (DIM * RANK);

    __shared__ float4 trig[64][TILE];                // [segment j][row-in-tile]

    float2 A[64];                                    // A[j]: carry of scan j (A[0] dead)
    #pragma unroll
    for (int j = 0; j < 64; ++j) A[j] = make_float2(0.f, 0.f);

    // phase-1 (rowJ) state for column c: segment j0 = 63-c
    const int j0   = 63 - c;
    const int len0 = NSEG0 + j0;                     // = 255-c; rowJ spans rows 0..len0
    float S = 1.f, Er = 1.f, Ei = 0.f;               // cumprod(sin t), prod(exp(i p))

    #pragma unroll 1
    for (int t0 = 0; t0 < DIM; t0 += TILE) {
        __syncthreads();                             // protect prior tile's readers
        for (int k = c; k < 64 * TILE; k += 64) {
            const int j  = k / TILE;
            const int ti = k % TILE;
            const int i  = t0 + ti;
            if (i < NSEG0 + j) {
                const int offj = NSEG0 * j + (j * (j - 1)) / 2;
                const float2 tp = tb[offj + i];
                trig[j][ti] = make_float4(__cosf(tp.x), __sinf(tp.x),
                                          __cosf(tp.y), __sinf(tp.y));
            }
        }
        __syncthreads();

        #pragma unroll 1
        for (int ti = 0; ti < TILE; ++ti) {
            const int i = t0 + ti;

            // ---- initial value of (row i, column c): rowJ from segment j0 ----
            float vr, vi;
            if (i < len0) {                          // interior rowJ element
                const float4 q = trig[j0][ti];
                const float Fr = Er * q.z + Ei * q.w;    // E * conj(e_i)
                const float Fi = Ei * q.z - Er * q.w;
                const float amp = q.x * S;               // ct_i * prod_{k<i} st_k
                vr = amp * Fr; vi = amp * Fi;
                S *= q.y;
                const float nEr = Er * q.z - Ei * q.w;   // E *= e_i
                const float nEi = Ei * q.z + Er * q.w;
                Er = nEr; Ei = nEi;
            } else if (i == len0) {                  // last rowJ element: S * E
                vr = S * Er; vi = S * Ei;
            } else {                                 // row will arrive via deposit
                vr = 0.f; vi = 0.f;
            }

            // ---- apply all scans touching row i, in increasing j ----
            #pragma unroll
            for (int j = 1; j < 64; ++j) {
                const int limit = NSEG0 + j;
                if (i > limit) continue;             // wave-uniform: scan j finished
                const bool act = (c >= 64 - j);      // column participates in scan j
                if (i == limit) {                    // deposit scan j's final carry
                    if (act) { vr = A[j].x; vi = A[j].y; }
                } else if (act) {                    // rotate (v, A[j])
                    const float4 q = trig[j][ti];    // broadcast read
                    const float ar = A[j].x, ai = A[j].y;
                    const float ur = q.x * ar - q.y * vr;   // u = ct*a - st*v
                    const float ui = q.x * ai - q.y * vi;
                    const float pr = q.x * vr + q.y * ar;   // p = ct*v + st*a
                    const float pi = q.x * vi + q.y * ai;
                    vr = ur * q.z + ui * q.w;               // z = u * conj(e)
                    vi = ui * q.z - ur * q.w;
                    A[j].x = pr * q.z - pi * q.w;           // a' = p * e
                    A[j].y = pr * q.w + pi * q.z;
                }
            }

            // ---- store REAL PART only (write-once, bounds-guarded) ----
            const long long oidx = obase + (long long)i * RANK + c;
            if (oidx < out_limit) out[oidx] = vr;
        }
    }
}

extern "C" void kernel_launch(void* const* d_in, const int* in_sizes, int n_in,
                              void* d_out, int out_size, void* d_ws, size_t ws_size,
                              hipStream_t stream)
{
    const float* theta = (const float*)d_in[0];
    float* out = (float*)d_out;
    const int batch = in_sizes[0] / (2 * N0);        // 1024 for this problem
    if (batch <= 0) return;

    stiefel_fused<<<batch, 64, 0, stream>>>(theta, out, (long long)out_size);
}

// Round 4
// 976.609 us; speedup vs baseline: 2.3258x; 2.3258x over previous
//
#include <hip/hip_runtime.h>

#define DIM   256
#define RANK  64
#define NSEG0 192                 // dim - rank = shortest segment
#define N0    14304               // sum_{j=0}^{63} (192+j) complex pairs per batch
#define NW    4                   // waves per block (scan bands)
#define TILE  16                  // rows per staged trig tile

// Wavefront-pipelined fused formulation.
// The (row i, scan j) lattice: node (i,j) needs (i,j-1) [value v flowing down
// the scans] and (i-1,j) [carry A_j flowing down the rows]. R3 ran it all in
// one wave (1 wave/SIMD, VALUBusy 37%, A[63] spilled). Here the 63 scans are
// split into 4 bands: wave w owns j in [16w .. 16w+15] (j=0 band slot is dead,
// masked by act=false). Rows stream through the waves as a 4-stage pipeline:
// wave w processes row i = s - w at step s; the 64-complex row vector passes
// between waves through parity-double-buffered LDS. One __syncthreads per step
// gives the cross-wave ordering; carry state per wave is A[16] = 32 VGPRs (no
// spill). Trig (cos t, sin t, cos p, sin p) staged per 16-row tile, per-band,
// double-buffered. Output = REAL part only (convention proven in R1-R3).
__global__ __launch_bounds__(256, 4)
void stiefel_pipe(const float* __restrict__ theta, float* __restrict__ out,
                  long long out_limit)
{
    const int b   = blockIdx.x;
    const int tid = threadIdx.x;
    const int w   = tid >> 6;                        // scan band 0..3
    const int c   = tid & 63;                        // column lane

    const float2* tb = (const float2*)theta + (size_t)b * N0;   // (t,p) pairs
    const long long obase = (long long)b * (DIM * RANK);

    __shared__ float4 trig[2][NW][16][TILE];         // [tile parity][band][seg][row] 32 KB
    __shared__ float2 pipe[NW - 1][2][64];           // [boundary][row parity][col] 3 KB

    const int jbase = 16 * w;                        // band's first segment

    float2 A[16];                                    // carries for scans jbase..jbase+15
    #pragma unroll
    for (int k = 0; k < 16; ++k) A[k] = make_float2(0.f, 0.f);

    // rowJ generator state (used by wave 0 only; lane c <-> segment j0 = 63-c)
    const int j0   = 63 - c;
    const int len0 = NSEG0 + j0;                     // = 255-c
    float S = 1.f, Er = 1.f, Ei = 0.f;

    // fast path valid while i < 192+j for every live j in the band
    const int fastlim = (w == 0) ? NSEG0 : (NSEG0 + jbase);

    #pragma unroll 1
    for (int s = 0; s < DIM + NW - 1; ++s) {
        // ---- stage trig tile T = s/16 (band-local segments) ----
        if ((s & (TILE - 1)) == 0 && s < DIM) {
            const int T    = s >> 4;
            const int p    = T & 1;
            const int segl = c >> 2;                 // 0..15 within band
            const int j    = jbase + segl;
            const int r0   = (c & 3) << 2;           // 0,4,8,12
            const int offj = NSEG0 * j + ((j * (j - 1)) >> 1);
            const int len  = NSEG0 + j;
            #pragma unroll
            for (int u = 0; u < 4; ++u) {
                const int i = (T << 4) + r0 + u;
                if (i < len) {
                    const float2 tp = tb[offj + i];
                    trig[p][w][segl][r0 + u] =
                        make_float4(__cosf(tp.x), __sinf(tp.x),
                                    __cosf(tp.y), __sinf(tp.y));
                }
            }
            __syncthreads();                         // staging visible to all bands
        }

        const int i = s - w;                         // this band's row this step
        if (i >= 0 && i < DIM) {
            const int p  = (i >> 4) & 1;
            const int ti = i & (TILE - 1);

            // ---- obtain v entering this band ----
            float vr, vi;
            if (w == 0) {                            // generate rowJ value
                if (i < len0) {
                    const float4 q = trig[p][3 - (c >> 4)][15 - (c & 15)][ti];
                    const float Fr = Er * q.z + Ei * q.w;   // E * conj(e_i)
                    const float Fi = Ei * q.z - Er * q.w;
                    const float amp = q.x * S;              // ct_i * prod st
                    vr = amp * Fr; vi = amp * Fi;
                    S *= q.y;
                    const float nEr = Er * q.z - Ei * q.w;  // E *= e_i
                    const float nEi = Ei * q.z + Er * q.w;
                    Er = nEr; Ei = nEi;
                } else if (i == len0) { vr = S * Er; vi = S * Ei; }
                else                  { vr = 0.f;    vi = 0.f;    }
            } else {
                const float2 vin = pipe[w - 1][i & 1][c];
                vr = vin.x; vi = vin.y;
            }

            // ---- apply this band's scans ----
            const float4* tq = &trig[p][w][0][ti];   // tq[16*k] = trig[p][w][k][ti]
            if (i < fastlim) {
                // straight-line: every k rotates (act-masked), no deposits
                #pragma unroll
                for (int k = 0; k < 16; ++k) {
                    const float4 q  = tq[16 * k];    // broadcast ds_read_b128
                    const bool  act = (c + jbase + k >= 64);
                    const float ar = A[k].x, ai = A[k].y;
                    const float ur = q.x * ar - q.y * vr;
                    const float ui = q.x * ai - q.y * vi;
                    const float pr = q.x * vr + q.y * ar;
                    const float pi = q.x * vi + q.y * ai;
                    const float zr = ur * q.z + ui * q.w;   // u * conj(e)
                    const float zi = ui * q.z - ur * q.w;
                    const float nar = pr * q.z - pi * q.w;  // p * e
                    const float nai = pr * q.w + pi * q.z;
                    if (act) { vr = zr; vi = zi; A[k].x = nar; A[k].y = nai; }
                }
            } else {
                // tail rows: mixed rotate / deposit / dead, per k
                #pragma unroll
                for (int k = 0; k < 16; ++k) {
                    const int j     = jbase + k;
                    const int limit = NSEG0 + j;
                    if (i > limit) continue;         // wave-uniform
                    const bool act = (c + j >= 64);
                    if (i == limit) {                // deposit band-k carry
                        if (act) { vr = A[k].x; vi = A[k].y; }
                    } else if (act) {
                        const float4 q = tq[16 * k];
                        const float ar = A[k].x, ai = A[k].y;
                        const float ur = q.x * ar - q.y * vr;
                        const float ui = q.x * ai - q.y * vi;
                        const float pr = q.x * vr + q.y * ar;
                        const float pi = q.x * vi + q.y * ai;
                        vr = ur * q.z + ui * q.w;
                        vi = ui * q.z - ur * q.w;
                        A[k].x = pr * q.z - pi * q.w;
                        A[k].y = pr * q.w + pi * q.z;
                    }
                }
            }

            // ---- pass v to next band / emit ----
            if (w < NW - 1) {
                pipe[w][i & 1][c] = make_float2(vr, vi);
            } else {
                const long long oidx = obase + (long long)i * RANK + c;
                if (oidx < out_limit) out[oidx] = vr;   // REAL part only
            }
        }
        __syncthreads();                             // step boundary
    }
}

extern "C" void kernel_launch(void* const* d_in, const int* in_sizes, int n_in,
                              void* d_out, int out_size, void* d_ws, size_t ws_size,
                              hipStream_t stream)
{
    const float* theta = (const float*)d_in[0];
    float* out = (float*)d_out;
    const int batch = in_sizes[0] / (2 * N0);        // 1024 for this problem
    if (batch <= 0) return;

    stiefel_pipe<<<batch, 64 * NW, 0, stream>>>(theta, out, (long long)out_size);
}

// Round 5
// 604.117 us; speedup vs baseline: 3.7599x; 1.6166x over previous
//
#include <hip/hip_runtime.h>

typedef float f2 __attribute__((ext_vector_type(2)));

#define DIM   256
#define RANK  64
#define NSEG0 192                 // dim - rank = shortest segment
#define N0    14304               // sum_{j=0}^{63} (192+j) complex pairs per batch
#define NW    4                   // waves per block (scan bands)
#define TILE  16                  // rows per staged trig tile

// Wavefront-pipelined fused formulation (R4 structure), round-5 upgrades:
//  * complex math on float2 vectors -> v_pk_fma_f32 (VOP3P) halves rotation VALU
//  * fast path fully branch-free (ternary selects only); A[k] updated
//    unconditionally (inactive-lane carries are never read: deposits are
//    act-selected, so garbage there is harmless) -> ds_reads hoistable
//  * trig LDS transposed to [parity][row][segment]: band reads stay broadcast,
//    wave-0 rowJ read becomes stride-16B (conflict-free; was 64-way)
//  * exactly one __syncthreads per step (staging overlaps prior step's compute:
//    it writes the parity slot whose last readers finished >=13 barriers ago)
// Output convention (proven R1-R3): d_out = REAL part, (batch,256,64) fp32.
__global__ __launch_bounds__(256, 4)
void stiefel_pipe(const float* __restrict__ theta, float* __restrict__ out,
                  long long out_limit)
{
    const int b   = blockIdx.x;
    const int tid = threadIdx.x;
    const int w   = tid >> 6;                        // scan band 0..3
    const int c   = tid & 63;                        // column lane

    const float2* tb = (const float2*)theta + (size_t)b * N0;   // (t,p) pairs
    const long long obase = (long long)b * (DIM * RANK);

    __shared__ float4 trigT[2][TILE][64];            // [parity][row][seg]  32 KB
    __shared__ float2 pipe[NW - 1][2][64];           // [boundary][row parity][col]

    const int jbase = 16 * w;

    f2 A[16];                                        // carries for scans jbase+k
    #pragma unroll
    for (int k = 0; k < 16; ++k) A[k] = (f2){0.f, 0.f};

    // staging constants: thread tid owns segment jS, rows rS..rS+3 of each tile
    const int jS   = tid & 63;
    const int rS   = (tid >> 6) << 2;                // 0,4,8,12
    const int offS = NSEG0 * jS + ((jS * (jS - 1)) >> 1);
    const int lenS = NSEG0 + jS;

    // rowJ generator state (wave 0; lane c <-> segment 63-c)
    const int len0 = NSEG0 + 63 - c;                 // = 255-c
    float S = 1.f, Er = 1.f, Ei = 0.f;

    // all 16 band scans are pure rotations while i < fastlim
    const int fastlim = NSEG0 + ((w == 0) ? 0 : jbase);

    #pragma unroll 1
    for (int s = 0; s < DIM + NW - 1; ++s) {
        // ---- stage trig tile (cos t, sin t, cos p, sin p) ----
        if ((s & (TILE - 1)) == 0 && s < DIM) {
            const int pS = (s >> 4) & 1;
            #pragma unroll
            for (int u = 0; u < 4; ++u) {
                const int i = s + rS + u;
                if (i < lenS) {
                    const float2 tp = tb[offS + i];
                    trigT[pS][rS + u][jS] =
                        make_float4(__cosf(tp.x), __sinf(tp.x),
                                    __cosf(tp.y), __sinf(tp.y));
                }
            }
        }
        __syncthreads();                             // the step boundary

        const int i = s - w;                         // this band's row this step
        if (i >= 0 && i < DIM) {
            const int p  = (i >> 4) & 1;
            const int ti = i & (TILE - 1);

            // ---- value entering this band ----
            f2 V;
            if (w == 0) {                            // generate rowJ value
                if (i < len0) {
                    const float4 q = trigT[p][ti][63 - c];  // stride-16B, conflict-free
                    const float Fr = Er * q.z + Ei * q.w;   // E * conj(e_i)
                    const float Fi = Ei * q.z - Er * q.w;
                    const float amp = q.x * S;              // ct_i * prod st
                    V = (f2){amp * Fr, amp * Fi};
                    S *= q.y;
                    const float nEr = Er * q.z - Ei * q.w;  // E *= e_i
                    const float nEi = Ei * q.z + Er * q.w;
                    Er = nEr; Ei = nEi;
                } else if (i == len0) { V = (f2){S * Er, S * Ei}; }
                else                  { V = (f2){0.f, 0.f}; }
            } else {
                const float2 vin = pipe[w - 1][i & 1][c];
                V = (f2){vin.x, vin.y};
            }

            const float4* tq = &trigT[p][ti][jbase]; // tq[k]: broadcast reads
            if (i < fastlim) {
                // branch-free: 16 rotations, V act-selected, A unconditional
                #pragma unroll
                for (int k = 0; k < 16; ++k) {
                    const float4 q = tq[k];
                    const bool act = (c >= 64 - jbase - k);     // j = jbase+k
                    const f2 ct2 = {q.x, q.x};
                    const f2 st2 = {q.y, q.y};
                    const f2 er2 = {q.z, q.z};
                    const f2 eis = {q.w, -q.w};
                    const f2 Ak  = A[k];
                    const f2 u   = ct2 * Ak - st2 * V;          // ct*a - st*v
                    const f2 pp  = ct2 * V + st2 * Ak;          // ct*v + st*a
                    const f2 us  = {u.y, u.x};
                    const f2 ps  = {pp.y, pp.x};
                    const f2 z   = er2 * u + eis * us;          // u * conj(e)
                    A[k]         = er2 * pp - eis * ps;         // p * e
                    V.x = act ? z.x : V.x;
                    V.y = act ? z.y : V.y;
                }
            } else {
                // tail rows: mixed rotate / deposit / dead per k (wave-uniform i)
                #pragma unroll
                for (int k = 0; k < 16; ++k) {
                    const int j = jbase + k;
                    const int limit = NSEG0 + j;
                    if (i > limit) continue;
                    const bool act = (c >= 64 - j);
                    if (i == limit) {                // deposit scan j's carry
                        V.x = act ? A[k].x : V.x;
                        V.y = act ? A[k].y : V.y;
                    } else {
                        const float4 q = tq[k];
                        const f2 ct2 = {q.x, q.x};
                        const f2 st2 = {q.y, q.y};
                        const f2 er2 = {q.z, q.z};
                        const f2 eis = {q.w, -q.w};
                        const f2 Ak  = A[k];
                        const f2 u   = ct2 * Ak - st2 * V;
                        const f2 pp  = ct2 * V + st2 * Ak;
                        const f2 us  = {u.y, u.x};
                        const f2 ps  = {pp.y, pp.x};
                        const f2 z   = er2 * u + eis * us;
                        A[k]         = er2 * pp - eis * ps;
                        V.x = act ? z.x : V.x;
                        V.y = act ? z.y : V.y;
                    }
                }
            }

            // ---- pass v to next band / emit real part ----
            if (w < NW - 1) {
                pipe[w][i & 1][c] = make_float2(V.x, V.y);
            } else {
                const long long oidx = obase + (long long)i * RANK + c;
                if (oidx < out_limit) out[oidx] = V.x;
            }
        }
    }
}

extern "C" void kernel_launch(void* const* d_in, const int* in_sizes, int n_in,
                              void* d_out, int out_size, void* d_ws, size_t ws_size,
                              hipStream_t stream)
{
    const float* theta = (const float*)d_in[0];
    float* out = (float*)d_out;
    const int batch = in_sizes[0] / (2 * N0);        // 1024 for this problem
    if (batch <= 0) return;

    stiefel_pipe<<<batch, 64 * NW, 0, stream>>>(theta, out, (long long)out_size);
}

// Round 6
// 575.473 us; speedup vs baseline: 3.9471x; 1.0498x over previous
//
#include <hip/hip_runtime.h>

typedef float f2 __attribute__((ext_vector_type(2)));

#define DIM   256
#define RANK  64
#define NSEG0 192                 // dim - rank = shortest segment
#define N0    14304               // sum_{j=0}^{63} (192+j) complex pairs per batch
#define NW    8                   // waves per block (scan bands of 8)
#define TILE  16                  // rows per staged trig tile

// Wavefront-pipelined fused formulation, NW=8 edition.
// R5 post-mortem: grid limited us to 4 waves/SIMD; VALUBusy 65% with ~35%
// dependency/barrier stall. Here the 63 scans split into 8 bands of 8
// (wave w owns j in [8w, 8w+8), j=0 slot dead) -> 8192 waves = 8 waves/SIMD
// (HW max). Carry state A[8] = 16 VGPRs; __launch_bounds__(512,8) caps VGPR
// at 64 so all 32 waves/CU are resident. LDS 39.9 KB x 4 blocks = 156 KB.
// Rows stream through waves as an 8-stage pipeline via parity-double-buffered
// LDS; one __syncthreads per step. Trig staged per 16-row tile, transposed
// [parity][row][segment] (broadcast band reads; conflict-free rowJ reads).
// Output convention (proven R1-R3): d_out = REAL part, (batch,256,64) fp32.
__global__ __launch_bounds__(64 * NW, NW)
void stiefel_pipe(const float* __restrict__ theta, float* __restrict__ out,
                  long long out_limit)
{
    const int b   = blockIdx.x;
    const int tid = threadIdx.x;
    const int w   = tid >> 6;                        // scan band 0..7
    const int c   = tid & 63;                        // column lane

    const float2* tb = (const float2*)theta + (size_t)b * N0;   // (t,p) pairs
    const long long obase = (long long)b * (DIM * RANK);

    __shared__ float4 trigT[2][TILE][64];            // [parity][row][seg]  32 KB
    __shared__ float2 pipe[NW - 1][2][64];           // [boundary][row parity][col] 7 KB

    const int jbase = 8 * w;

    f2 A[8];                                         // carries for scans jbase+k
    #pragma unroll
    for (int k = 0; k < 8; ++k) A[k] = (f2){0.f, 0.f};

    // staging: thread tid owns segment jS, rows rS..rS+1 of each 16-row tile
    const int jS   = tid & 63;
    const int rS   = (tid >> 6) << 1;                // 0,2,..,14
    const int offS = NSEG0 * jS + ((jS * (jS - 1)) >> 1);
    const int lenS = NSEG0 + jS;

    // rowJ generator state (wave 0; lane c <-> segment 63-c)
    const int len0 = NSEG0 + 63 - c;                 // = 255-c
    float S = 1.f, Er = 1.f, Ei = 0.f;

    // all band scans are pure rotations while i < fastlim
    const int fastlim = NSEG0 + ((w == 0) ? 0 : jbase);

    #pragma unroll 1
    for (int s = 0; s < DIM + NW - 1; ++s) {
        // ---- stage trig tile (cos t, sin t, cos p, sin p) ----
        if ((s & (TILE - 1)) == 0 && s < DIM) {
            const int pS = (s >> 4) & 1;
            #pragma unroll
            for (int u = 0; u < 2; ++u) {
                const int i = s + rS + u;
                if (i < lenS) {
                    const float2 tp = tb[offS + i];
                    trigT[pS][rS + u][jS] =
                        make_float4(__cosf(tp.x), __sinf(tp.x),
                                    __cosf(tp.y), __sinf(tp.y));
                }
            }
        }
        __syncthreads();                             // the step boundary

        const int i = s - w;                         // this band's row this step
        if (i >= 0 && i < DIM) {
            const int p  = (i >> 4) & 1;
            const int ti = i & (TILE - 1);

            // ---- value entering this band ----
            f2 V;
            if (w == 0) {                            // generate rowJ value
                if (i < len0) {
                    const float4 q = trigT[p][ti][63 - c];
                    const float Fr = Er * q.z + Ei * q.w;   // E * conj(e_i)
                    const float Fi = Ei * q.z - Er * q.w;
                    const float amp = q.x * S;              // ct_i * prod st
                    V = (f2){amp * Fr, amp * Fi};
                    S *= q.y;
                    const float nEr = Er * q.z - Ei * q.w;  // E *= e_i
                    const float nEi = Ei * q.z + Er * q.w;
                    Er = nEr; Ei = nEi;
                } else if (i == len0) { V = (f2){S * Er, S * Ei}; }
                else                  { V = (f2){0.f, 0.f}; }
            } else {
                const float2 vin = pipe[w - 1][i & 1][c];
                V = (f2){vin.x, vin.y};
            }

            const float4* tq = &trigT[p][ti][jbase]; // tq[k]: broadcast reads
            if (i < fastlim) {
                // branch-free: 8 rotations, V act-selected, A unconditional
                #pragma unroll
                for (int k = 0; k < 8; ++k) {
                    const float4 q = tq[k];
                    const bool act = (c >= 64 - jbase - k);     // j = jbase+k
                    const f2 ct2 = {q.x, q.x};
                    const f2 st2 = {q.y, q.y};
                    const f2 er2 = {q.z, q.z};
                    const f2 eis = {q.w, -q.w};
                    const f2 Ak  = A[k];
                    const f2 u   = ct2 * Ak - st2 * V;          // ct*a - st*v
                    const f2 pp  = ct2 * V + st2 * Ak;          // ct*v + st*a
                    const f2 us  = {u.y, u.x};
                    const f2 ps  = {pp.y, pp.x};
                    const f2 z   = er2 * u + eis * us;          // u * conj(e)
                    A[k]         = er2 * pp - eis * ps;         // p * e
                    V.x = act ? z.x : V.x;
                    V.y = act ? z.y : V.y;
                }
            } else {
                // tail rows: mixed rotate / deposit / dead per k (wave-uniform i)
                #pragma unroll
                for (int k = 0; k < 8; ++k) {
                    const int j = jbase + k;
                    const int limit = NSEG0 + j;
                    if (i > limit) continue;
                    const bool act = (c >= 64 - j);
                    if (i == limit) {                // deposit scan j's carry
                        V.x = act ? A[k].x : V.x;
                        V.y = act ? A[k].y : V.y;
                    } else {
                        const float4 q = tq[k];
                        const f2 ct2 = {q.x, q.x};
                        const f2 st2 = {q.y, q.y};
                        const f2 er2 = {q.z, q.z};
                        const f2 eis = {q.w, -q.w};
                        const f2 Ak  = A[k];
                        const f2 u   = ct2 * Ak - st2 * V;
                        const f2 pp  = ct2 * V + st2 * Ak;
                        const f2 us  = {u.y, u.x};
                        const f2 ps  = {pp.y, pp.x};
                        const f2 z   = er2 * u + eis * us;
                        A[k]         = er2 * pp - eis * ps;
                        V.x = act ? z.x : V.x;
                        V.y = act ? z.y : V.y;
                    }
                }
            }

            // ---- pass v to next band / emit real part ----
            if (w < NW - 1) {
                pipe[w][i & 1][c] = make_float2(V.x, V.y);
            } else {
                const long long oidx = obase + (long long)i * RANK + c;
                if (oidx < out_limit) out[oidx] = V.x;
            }
        }
    }
}

extern "C" void kernel_launch(void* const* d_in, const int* in_sizes, int n_in,
                              void* d_out, int out_size, void* d_ws, size_t ws_size,
                              hipStream_t stream)
{
    const float* theta = (const float*)d_in[0];
    float* out = (float*)d_out;
    const int batch = in_sizes[0] / (2 * N0);        // 1024 for this problem
    if (batch <= 0) return;

    stiefel_pipe<<<batch, 64 * NW, 0, stream>>>(theta, out, (long long)out_size);
}